// Round 3
// baseline (582.412 us; speedup 1.0000x reference)
//
#include <hip/hip_runtime.h>
#include <hip/hip_bf16.h>

// Dtype conclusions (rounds 0-2 post-mortem):
//  - M/columns/W/b are fp32 on device (round 1: bf16 reads of M -> NaN).
//  - d_out is fp32 (round 2: bf16 writes -> same-scale garble, absmax 142.5
//    == bf16-pairs-read-as-fp32 signature; template contract: output dtype
//    follows the reference, which returns float32).
//  - sequence_lengths: int32 per template, but auto-detect int64 in-kernel.

// ---------------------------------------------------------------------------
// Kernel A: soft_argmax per row. One wave64 per row of M (ncol fp32).
// Lane loads float4 chunks (coalesced 1 KiB/wave-inst), FMA vs exact column
// index, wave64 butterfly reduce; lane 0 writes fp32 sa (ws) + fp32 relpos.
// ---------------------------------------------------------------------------
__global__ void __launch_bounds__(256) soft_argmax_kernel(
    const float* __restrict__ M, float* __restrict__ sa,
    float* __restrict__ relpos, int total, int ncol, float inv_ncol) {
  int wave = (blockIdx.x * blockDim.x + threadIdx.x) >> 6;
  int lane = threadIdx.x & 63;
  if (wave >= total) return;

  const float4* rowv = reinterpret_cast<const float4*>(M + (size_t)wave * ncol);
  int nchunk = ncol >> 2;  // float4 chunks per row
  float acc = 0.0f;
  for (int c = lane; c < nchunk; c += 64) {
    float4 u = rowv[c];
    float j = (float)(c << 2);
    acc = fmaf(u.x, j + 0.0f, acc);
    acc = fmaf(u.y, j + 1.0f, acc);
    acc = fmaf(u.z, j + 2.0f, acc);
    acc = fmaf(u.w, j + 3.0f, acc);
  }
  #pragma unroll
  for (int off = 32; off > 0; off >>= 1) acc += __shfl_xor(acc, off, 64);
  if (lane == 0) {
    sa[wave] = acc;
    relpos[wave] = acc * inv_ncol;
  }
}

// ---------------------------------------------------------------------------
// Kernel B: inclusive cumsum of sequence_lengths (nseq <= 1024), one block.
// Auto-detects int64 payload: if the high int32 word of every probed entry
// is zero (and lengths are positive), treat the buffer as int64 low words.
// Probe limited to nseq/2 entries so it stays in-bounds for the int32 case.
// ---------------------------------------------------------------------------
__global__ void scan_kernel(const int* __restrict__ len32, int* __restrict__ cs,
                            int nseq) {
  __shared__ int buf[1024];
  __shared__ int hi_nonzero;
  int t = threadIdx.x;
  if (t == 0) hi_nonzero = 0;
  __syncthreads();
  if (t < (nseq >> 1)) {
    if (len32[2 * t + 1] != 0) atomicOr(&hi_nonzero, 1);
  }
  __syncthreads();
  bool is64 = (hi_nonzero == 0);
  buf[t] = (t < nseq) ? (is64 ? len32[2 * t] : len32[t]) : 0;
  __syncthreads();
  for (int off = 1; off < nseq; off <<= 1) {
    int add = (t >= off) ? buf[t - off] : 0;
    __syncthreads();
    buf[t] += add;
    __syncthreads();
  }
  if (t < nseq) cs[t] = buf[t];
}

// ---------------------------------------------------------------------------
// Kernel C: boundary + interior gaps. One block per sequence.
// gaps_in output position for gap index g in sequence s is g - s (the s
// removed boundary gaps precede it in the kept list).
// ---------------------------------------------------------------------------
__global__ void gaps_kernel(const float* __restrict__ sa,
                            const int* __restrict__ cs,
                            float* __restrict__ gstart,
                            float* __restrict__ gin,
                            float* __restrict__ gend,
                            float inv_ncol, float ncolf) {
  int s = blockIdx.x;
  int end = cs[s];
  int prev = (s == 0) ? 0 : cs[s - 1];
  if (threadIdx.x == 0) {
    gstart[s] = sa[prev] * inv_ncol;
    gend[s]   = (ncolf - sa[end - 1] - 1.0f) * inv_ncol;
  }
  int ngap = end - 1 - prev;  // len - 1 interior gaps
  int outbase = prev - s;
  for (int t = threadIdx.x; t < ngap; t += blockDim.x) {
    gin[outbase + t] = (sa[prev + t + 1] - sa[prev + t] - 1.0f) * inv_ncol;
  }
}

// ---------------------------------------------------------------------------
// Kernel D: col_dist = softmax(columns @ W + b). 8 rows/block, 256 threads.
// Thread t -> (row_local = t>>5, o = t&31); nout (26) padded to 32.
// Rows staged fp32 in LDS; W read from global (L2-resident, ~6.8 MB total).
// ---------------------------------------------------------------------------
__global__ void __launch_bounds__(256) coldist_kernel(
    const float* __restrict__ columns, const float* __restrict__ W,
    const float* __restrict__ b, float* __restrict__ out, int dcol, int nout) {
  const int ROWS = 8;
  extern __shared__ float rowsf[];  // ROWS*dcol floats + 32 for bias

  int t = threadIdx.x;
  int row0 = blockIdx.x * ROWS;
  const float4* Cv = reinterpret_cast<const float4*>(columns + (size_t)row0 * dcol);
  float4* Lv = reinterpret_cast<float4*>(rowsf);
  int nCv = (ROWS * dcol) >> 2;
  for (int i = t; i < nCv; i += 256) Lv[i] = Cv[i];
  float* bf = rowsf + ROWS * dcol;
  if (t < 32) bf[t] = (t < nout) ? b[t] : 0.0f;
  __syncthreads();

  int o = t & 31;
  int rl = t >> 5;
  int oc = (o < nout) ? o : (nout - 1);  // clamp to avoid OOB W reads
  const float* rp = rowsf + rl * dcol;
  float acc = bf[oc];
  #pragma unroll 4
  for (int k = 0; k < dcol; k++) acc = fmaf(rp[k], W[k * nout + oc], acc);
  if (o >= nout) acc = -3.0e38f;

  float mx = acc;
  #pragma unroll
  for (int off = 16; off > 0; off >>= 1) mx = fmaxf(mx, __shfl_xor(mx, off, 32));
  float e = (o < nout) ? __expf(acc - mx) : 0.0f;
  float ssum = e;
  #pragma unroll
  for (int off = 16; off > 0; off >>= 1) ssum += __shfl_xor(ssum, off, 32);
  if (o < nout)
    out[(size_t)(row0 + rl) * nout + o] = e / ssum;
}

// ---------------------------------------------------------------------------
extern "C" void kernel_launch(void* const* d_in, const int* in_sizes, int n_in,
                              void* d_out, int out_size, void* d_ws,
                              size_t ws_size, hipStream_t stream) {
  const float* M       = (const float*)d_in[0];
  const float* columns = (const float*)d_in[1];
  const int*   seqlen  = (const int*)d_in[2];
  const float* W       = (const float*)d_in[3];
  const float* b       = (const float*)d_in[4];

  int nout  = in_sizes[4];
  int dcol  = in_sizes[3] / nout;
  int ncol  = in_sizes[1] / dcol;
  int total = in_sizes[0] / ncol;
  int nseq  = in_sizes[2];

  float* out     = (float*)d_out;
  float* out_rel = out;                       // [total]
  float* out_gs  = out_rel + total;           // [nseq]
  float* out_gi  = out_gs + nseq;             // [total - nseq]
  float* out_ge  = out_gi + (total - nseq);   // [nseq]
  float* out_cd  = out_ge + nseq;             // [ncol * nout]

  float* sa = (float*)d_ws;
  int* cs = (int*)((char*)d_ws + (((size_t)total * 4 + 255) & ~(size_t)255));

  float inv_ncol = 1.0f / (float)ncol;

  // A: one wave per row, 4 waves (256 threads) per block
  int blocksA = (total + 3) / 4;
  hipLaunchKernelGGL(soft_argmax_kernel, dim3(blocksA), dim3(256), 0, stream,
                     M, sa, out_rel, total, ncol, inv_ncol);
  // B: cumsum of sequence lengths
  hipLaunchKernelGGL(scan_kernel, dim3(1), dim3(1024), 0, stream, seqlen, cs,
                     nseq);
  // C: gap outputs, one block per sequence
  hipLaunchKernelGGL(gaps_kernel, dim3(nseq), dim3(256), 0, stream, sa, cs,
                     out_gs, out_gi, out_ge, inv_ncol, (float)ncol);
  // D: col_dist softmax
  const int ROWS = 8;
  size_t lds = (size_t)ROWS * dcol * 4 + 32 * 4;
  hipLaunchKernelGGL(coldist_kernel, dim3(ncol / ROWS), dim3(256), lds, stream,
                     columns, W, b, out_cd, dcol, nout);
}

// Round 4
// 555.499 us; speedup vs baseline: 1.0484x; 1.0484x over previous
//
#include <hip/hip_runtime.h>
#include <hip/hip_bf16.h>

// Dtype facts (rounds 0-3): M/columns/W/b fp32; d_out fp32; sequence_lengths
// auto-detected int32 vs int64 (probe high words). Round 3 PASSED (absmax
// 0.0625) -- layout and gap indexing verified.
//
// Round-4 structure: 2 launches.
//  K1: blocks [0,NBLK_CD) -> col_dist softmax (overlaps the M stream);
//      blocks [NBLK_CD, ...) -> grid-strided soft-argmax, writes relpos only.
//  K2: per-sequence gaps; each block recomputes its own length prefix in-block
//      (500 ints, L2-resident) -- no scan kernel, no ws dependency at all.

#define CD_ROWS 8
#define CD_MAXD 512
#define A_BLOCKS 1920

__global__ void __launch_bounds__(256) fused_main_kernel(
    const float* __restrict__ M, const float* __restrict__ columns,
    const float* __restrict__ W, const float* __restrict__ b,
    float* __restrict__ relpos, float* __restrict__ out_cd, int total,
    int ncol, float inv_ncol, int dcol, int nout, int nblk_cd) {
  __shared__ float smem_f[CD_ROWS * CD_MAXD + 64];
  int t = threadIdx.x;

  if ((int)blockIdx.x < nblk_cd) {
    // ---------------- col_dist branch (dispatched first, overlaps stream) ---
    int row0 = blockIdx.x * CD_ROWS;
    bool lds_ok = (dcol <= CD_MAXD);
    if (lds_ok) {
      const float4* Cv =
          reinterpret_cast<const float4*>(columns + (size_t)row0 * dcol);
      float4* Lv = reinterpret_cast<float4*>(smem_f);
      int nCv = (CD_ROWS * dcol) >> 2;
      for (int i = t; i < nCv; i += 256) Lv[i] = Cv[i];
    }
    float* bf = smem_f + CD_ROWS * CD_MAXD;
    if (t < 32) bf[t] = (t < nout) ? b[t] : 0.0f;
    __syncthreads();

    int o = t & 31;
    int rl = t >> 5;
    int oc = (o < nout) ? o : (nout - 1);  // clamp avoids OOB W reads
    const float* rp = lds_ok ? (smem_f + rl * dcol)
                             : (columns + (size_t)(row0 + rl) * dcol);
    float acc = bf[oc];
    #pragma unroll 4
    for (int k = 0; k < dcol; k++) acc = fmaf(rp[k], W[k * nout + oc], acc);
    if (o >= nout) acc = -3.0e38f;

    float mx = acc;
    #pragma unroll
    for (int off = 16; off > 0; off >>= 1)
      mx = fmaxf(mx, __shfl_xor(mx, off, 32));
    float e = (o < nout) ? __expf(acc - mx) : 0.0f;
    float ssum = e;
    #pragma unroll
    for (int off = 16; off > 0; off >>= 1) ssum += __shfl_xor(ssum, off, 32);
    if (o < nout) out_cd[(size_t)(row0 + rl) * nout + o] = e / ssum;
    return;
  }

  // ---------------- soft-argmax branch: one wave64 per row, grid-strided ----
  int lane = t & 63;
  int wavesPerBlk = blockDim.x >> 6;
  int wslot = (blockIdx.x - nblk_cd) * wavesPerBlk + (t >> 6);
  int nwaves = (gridDim.x - nblk_cd) * wavesPerBlk;
  int nchunk = ncol >> 2;  // float4 chunks per row

  for (int row = wslot; row < total; row += nwaves) {
    const float4* rowv =
        reinterpret_cast<const float4*>(M + (size_t)row * ncol);
    float acc = 0.0f;
    if (nchunk == 256) {
      // ncol == 1024 fast path: 4 loads issued back-to-back (max outstanding)
      float4 u0 = rowv[lane];
      float4 u1 = rowv[lane + 64];
      float4 u2 = rowv[lane + 128];
      float4 u3 = rowv[lane + 192];
      float j0 = (float)(lane << 2);
      float j1 = j0 + 256.0f, j2 = j0 + 512.0f, j3 = j0 + 768.0f;
      acc = fmaf(u0.x, j0, acc);
      acc = fmaf(u0.y, j0 + 1.0f, acc);
      acc = fmaf(u0.z, j0 + 2.0f, acc);
      acc = fmaf(u0.w, j0 + 3.0f, acc);
      acc = fmaf(u1.x, j1, acc);
      acc = fmaf(u1.y, j1 + 1.0f, acc);
      acc = fmaf(u1.z, j1 + 2.0f, acc);
      acc = fmaf(u1.w, j1 + 3.0f, acc);
      acc = fmaf(u2.x, j2, acc);
      acc = fmaf(u2.y, j2 + 1.0f, acc);
      acc = fmaf(u2.z, j2 + 2.0f, acc);
      acc = fmaf(u2.w, j2 + 3.0f, acc);
      acc = fmaf(u3.x, j3, acc);
      acc = fmaf(u3.y, j3 + 1.0f, acc);
      acc = fmaf(u3.z, j3 + 2.0f, acc);
      acc = fmaf(u3.w, j3 + 3.0f, acc);
    } else {
      for (int c = lane; c < nchunk; c += 64) {
        float4 u = rowv[c];
        float j = (float)(c << 2);
        acc = fmaf(u.x, j + 0.0f, acc);
        acc = fmaf(u.y, j + 1.0f, acc);
        acc = fmaf(u.z, j + 2.0f, acc);
        acc = fmaf(u.w, j + 3.0f, acc);
      }
    }
    #pragma unroll
    for (int off = 32; off > 0; off >>= 1) acc += __shfl_xor(acc, off, 64);
    if (lane == 0) relpos[row] = acc * inv_ncol;
  }
}

// ---------------------------------------------------------------------------
// K2: per-sequence gaps, one block per sequence. Each block recomputes its
// own prefix-sum of lengths (nseq ints, L2-resident). All outputs derived
// from relpos: gstart=relpos[prev], gend=1-1/ncol-relpos[end-1],
// gin[g] = relpos[prev+g+1]-relpos[prev+g]-1/ncol at output index prev-s+g.
// ---------------------------------------------------------------------------
__global__ void __launch_bounds__(256) gaps_kernel(
    const float* __restrict__ relpos, const int* __restrict__ len32,
    float* __restrict__ gstart, float* __restrict__ gin,
    float* __restrict__ gend, int nseq, float inv_ncol) {
  __shared__ int sh_red[4];
  __shared__ int sh_prev, sh_len, sh_hi;
  int s = blockIdx.x;
  int t = threadIdx.x;

  if (t == 0) sh_hi = 0;
  __syncthreads();
  // int64 detect: probe high words of the first nseq/2 entries (in-bounds for
  // both layouts). All-zero high words + positive lengths => int64 payload.
  if (t < (nseq >> 1) && len32[2 * t + 1] != 0) atomicOr(&sh_hi, 1);
  __syncthreads();
  bool is64 = (sh_hi == 0);

  int part = 0;
  for (int k = t; k < nseq; k += 256) {
    int L = is64 ? len32[2 * k] : len32[k];
    if (k < s) part += L;
    if (k == s) sh_len = L;  // exactly one writer
  }
  #pragma unroll
  for (int off = 32; off > 0; off >>= 1) part += __shfl_xor(part, off, 64);
  if ((t & 63) == 0) sh_red[t >> 6] = part;
  __syncthreads();
  if (t == 0) sh_prev = sh_red[0] + sh_red[1] + sh_red[2] + sh_red[3];
  __syncthreads();

  int prev = sh_prev;
  int L = sh_len;
  int end = prev + L;
  if (t == 0) {
    gstart[s] = relpos[prev];
    gend[s] = 1.0f - inv_ncol - relpos[end - 1];
  }
  int outbase = prev - s;
  for (int g = t; g < L - 1; g += 256)
    gin[outbase + g] = relpos[prev + g + 1] - relpos[prev + g] - inv_ncol;
}

// ---------------------------------------------------------------------------
extern "C" void kernel_launch(void* const* d_in, const int* in_sizes, int n_in,
                              void* d_out, int out_size, void* d_ws,
                              size_t ws_size, hipStream_t stream) {
  const float* M       = (const float*)d_in[0];
  const float* columns = (const float*)d_in[1];
  const int*   seqlen  = (const int*)d_in[2];
  const float* W       = (const float*)d_in[3];
  const float* b       = (const float*)d_in[4];

  int nout  = in_sizes[4];
  int dcol  = in_sizes[3] / nout;
  int ncol  = in_sizes[1] / dcol;
  int total = in_sizes[0] / ncol;
  int nseq  = in_sizes[2];

  float* out     = (float*)d_out;
  float* out_rel = out;                       // [total]
  float* out_gs  = out_rel + total;           // [nseq]
  float* out_gi  = out_gs + nseq;             // [total - nseq]
  float* out_ge  = out_gi + (total - nseq);   // [nseq]
  float* out_cd  = out_ge + nseq;             // [ncol * nout]

  float inv_ncol = 1.0f / (float)ncol;
  int nblk_cd = (ncol + CD_ROWS - 1) / CD_ROWS;  // 128 for ncol=1024

  // K1: col_dist blocks first (overlap the stream), then soft-argmax blocks.
  hipLaunchKernelGGL(fused_main_kernel, dim3(nblk_cd + A_BLOCKS), dim3(256), 0,
                     stream, M, columns, W, b, out_rel, out_cd, total, ncol,
                     inv_ncol, dcol, nout, nblk_cd);
  // K2: gaps (depends only on relpos region of d_out)
  hipLaunchKernelGGL(gaps_kernel, dim3(nseq), dim3(256), 0, stream, out_rel,
                     seqlen, out_gs, out_gi, out_ge, nseq, inv_ncol);
}